// Round 6
// baseline (80.527 us; speedup 1.0000x reference)
//
#include <hip/hip_runtime.h>

// LIF recurrence: T=128 timesteps, N neurons (fp32).
//   v = BETA*v + I[t] - GAMMA*s ;  s = (v > 1) ;  v = v*(1-s)
// Outputs concatenated flat: spikes (T*N) | v_mem (T*N) | spikes (T*N).
//
// Ladder: r1 float4 plain = 102us; r4 float4 + plain-load + NT-STORE = 75.6us
// (L3 absorbs the read stream; 7.1 TB/s logical); r5 float2 variant = 79.2us
// (narrower stores lose more than 2x waves gains).
// Round-6: raise TLP withOUT narrowing stores — T-split x2 with redundant
// recompute. Chunk-0 blocks own t=0..63; chunk-1 blocks own t=64..127 and
// first recompute the carry (load+compute only, bit-identical __f*_rn ops
// => exact same v,s at the handoff; reads are L3-resident so the prelude is
// cheap and overlaps chunk-0's store phase). 2 waves/SIMD, full float4 nt
// stores everywhere.
//
// NOTE: spike threshold (v > 1.0f) is a hard decision boundary. To match the
// numpy reference bit-exactly we replicate its per-op fp32 rounding:
// ((BETA*v + I) - GAMMA*s) with NO fma contraction (__fmul_rn/__fadd_rn/
// __fsub_rn). The reset v*(1-s) is exactly (s ? 0 : v) since s is 0 or 1.

#define T_STEPS 128
#define SPLIT 2
#define T_CHUNK (T_STEPS / SPLIT)
#define BETA_F 0.95f
#define GAMMA_F 0.95f
#define VTH_F 1.0f

typedef float f32x4 __attribute__((ext_vector_type(4)));

#define LIF_STEP(in)                                                            \
    do {                                                                        \
        vx = __fsub_rn(__fadd_rn(__fmul_rn(BETA_F, vx), (in).x), __fmul_rn(GAMMA_F, sx)); \
        vy = __fsub_rn(__fadd_rn(__fmul_rn(BETA_F, vy), (in).y), __fmul_rn(GAMMA_F, sy)); \
        vz = __fsub_rn(__fadd_rn(__fmul_rn(BETA_F, vz), (in).z), __fmul_rn(GAMMA_F, sz)); \
        vw = __fsub_rn(__fadd_rn(__fmul_rn(BETA_F, vw), (in).w), __fmul_rn(GAMMA_F, sw)); \
        sx = (vx > VTH_F) ? 1.0f : 0.0f;                                        \
        sy = (vy > VTH_F) ? 1.0f : 0.0f;                                        \
        sz = (vz > VTH_F) ? 1.0f : 0.0f;                                        \
        sw = (vw > VTH_F) ? 1.0f : 0.0f;                                        \
        vx = (sx != 0.0f) ? 0.0f : vx;                                          \
        vy = (sy != 0.0f) ? 0.0f : vy;                                          \
        vz = (sz != 0.0f) ? 0.0f : vz;                                          \
        vw = (sw != 0.0f) ? 0.0f : vw;                                          \
    } while (0)

__global__ __launch_bounds__(256) void lif_kernel(
    const f32x4* __restrict__ I4,
    f32x4* __restrict__ s_out,   // spikes, first copy
    f32x4* __restrict__ v_out,   // v_mem
    f32x4* __restrict__ s_out2,  // spikes, second copy
    int n4)                      // N/4
{
    const int nblk = gridDim.x / SPLIT;        // blocks per chunk
    const int chunk = blockIdx.x / nblk;       // 0..SPLIT-1
    const int bcol = blockIdx.x % nblk;
    const int idx = bcol * blockDim.x + threadIdx.x;
    if (idx >= n4) return;

    float vx = 0.f, vy = 0.f, vz = 0.f, vw = 0.f;
    float sx = 0.f, sy = 0.f, sz = 0.f, sw = 0.f;

    size_t off = (size_t)idx;
    const int t0 = chunk * T_CHUNK;

    // Prelude: recompute carry for t < t0 (no stores). Zero-trip for chunk 0.
    #pragma unroll 8
    for (int t = 0; t < t0; ++t, off += (size_t)n4) {
        f32x4 in = I4[off];
        LIF_STEP(in);
    }

    // Active phase: own t0 .. t0+T_CHUNK-1, store all three outputs.
    #pragma unroll 8
    for (int t = 0; t < T_CHUNK; ++t, off += (size_t)n4) {
        f32x4 in = I4[off];
        LIF_STEP(in);
        f32x4 sv; sv.x = sx; sv.y = sy; sv.z = sz; sv.w = sw;
        f32x4 vv; vv.x = vx; vv.y = vy; vv.z = vz; vv.w = vw;
        __builtin_nontemporal_store(sv, &s_out[off]);
        __builtin_nontemporal_store(vv, &v_out[off]);
        __builtin_nontemporal_store(sv, &s_out2[off]);
    }
}

extern "C" void kernel_launch(void* const* d_in, const int* in_sizes, int n_in,
                              void* d_out, int out_size, void* d_ws, size_t ws_size,
                              hipStream_t stream) {
    const float* I = (const float*)d_in[0];
    float* out = (float*)d_out;

    const int TN = in_sizes[0];        // T * N
    const int N = TN / T_STEPS;
    const int n4 = N / 4;

    float* s0 = out;
    float* vm = out + (size_t)TN;
    float* s1 = out + 2 * (size_t)TN;

    const int block = 256;
    const int nblk = (n4 + block - 1) / block;
    const int grid = nblk * SPLIT;

    lif_kernel<<<grid, block, 0, stream>>>(
        (const f32x4*)I, (f32x4*)s0, (f32x4*)vm, (f32x4*)s1, n4);
}

// Round 7
// 75.617 us; speedup vs baseline: 1.0649x; 1.0649x over previous
//
#include <hip/hip_runtime.h>

// LIF recurrence: T=128 timesteps, N neurons (fp32).
//   v = BETA*v + I[t] - GAMMA*s ;  s = (v > 1) ;  v = v*(1-s)
// Outputs concatenated flat: spikes (T*N) | v_mem (T*N) | spikes (T*N).
//
// Ladder: r1 float4 plain = 102us; r4 float4 + plain-load + NT-STORE = 75.6us
// (L3 absorbs the read stream); r5 float2 = 79.2us; r6 T-split = 80.5us
// (both TLP experiments regressed -> TLP not the limiter).
// Round-7: vmcnt on CDNA is a single IN-ORDER counter for loads AND stores.
// Naive unroll-8 issues next group's loads AFTER 24 nt-stores, so each
// load-wait drains the store queue to HBM (~600cyc bubble x 16 groups at
// 1 wave/SIMD). Fix: 2-stage software pipeline — prefetch group g+1's loads
// BEFORE group g's stores, so load-waits never have older stores outstanding.
// Stores drain only once, at kernel end.
//
// NOTE: spike threshold (v > 1.0f) is a hard decision boundary. To match the
// numpy reference bit-exactly we replicate its per-op fp32 rounding:
// ((BETA*v + I) - GAMMA*s) with NO fma contraction (__fmul_rn/__fadd_rn/
// __fsub_rn). The reset v*(1-s) is exactly (s ? 0 : v) since s is 0 or 1.

#define T_STEPS 128
#define GROUP 8
#define NGROUP (T_STEPS / GROUP)   // 16
#define BETA_F 0.95f
#define GAMMA_F 0.95f
#define VTH_F 1.0f

typedef float f32x4 __attribute__((ext_vector_type(4)));

#define LIF_STEP(in)                                                            \
    do {                                                                        \
        vx = __fsub_rn(__fadd_rn(__fmul_rn(BETA_F, vx), (in).x), __fmul_rn(GAMMA_F, sx)); \
        vy = __fsub_rn(__fadd_rn(__fmul_rn(BETA_F, vy), (in).y), __fmul_rn(GAMMA_F, sy)); \
        vz = __fsub_rn(__fadd_rn(__fmul_rn(BETA_F, vz), (in).z), __fmul_rn(GAMMA_F, sz)); \
        vw = __fsub_rn(__fadd_rn(__fmul_rn(BETA_F, vw), (in).w), __fmul_rn(GAMMA_F, sw)); \
        sx = (vx > VTH_F) ? 1.0f : 0.0f;                                        \
        sy = (vy > VTH_F) ? 1.0f : 0.0f;                                        \
        sz = (vz > VTH_F) ? 1.0f : 0.0f;                                        \
        sw = (vw > VTH_F) ? 1.0f : 0.0f;                                        \
        vx = (sx != 0.0f) ? 0.0f : vx;                                          \
        vy = (sy != 0.0f) ? 0.0f : vy;                                          \
        vz = (sz != 0.0f) ? 0.0f : vz;                                          \
        vw = (sw != 0.0f) ? 0.0f : vw;                                          \
    } while (0)

__global__ __launch_bounds__(256) void lif_kernel(
    const f32x4* __restrict__ I4,
    f32x4* __restrict__ s_out,   // spikes, first copy
    f32x4* __restrict__ v_out,   // v_mem
    f32x4* __restrict__ s_out2,  // spikes, second copy
    int n4)                      // N/4
{
    const int idx = blockIdx.x * blockDim.x + threadIdx.x;
    if (idx >= n4) return;

    float vx = 0.f, vy = 0.f, vz = 0.f, vw = 0.f;
    float sx = 0.f, sy = 0.f, sz = 0.f, sw = 0.f;

    const size_t stride = (size_t)n4;
    size_t loadOff  = (size_t)idx;
    size_t storeOff = (size_t)idx;

    f32x4 buf[GROUP];

    // Prologue: load group 0.
    #pragma unroll
    for (int j = 0; j < GROUP; ++j)
        buf[j] = I4[loadOff + (size_t)j * stride];
    loadOff += (size_t)GROUP * stride;

    // Fully unrolled outer loop -> all buf/nbuf indices static (registers).
    #pragma unroll
    for (int g = 0; g < NGROUP; ++g) {
        f32x4 nbuf[GROUP];
        // Prefetch group g+1 BEFORE any store of group g (keeps load-waits
        // free of older outstanding stores under in-order vmcnt).
        if (g + 1 < NGROUP) {
            #pragma unroll
            for (int j = 0; j < GROUP; ++j)
                nbuf[j] = I4[loadOff + (size_t)j * stride];
        }
        loadOff += (size_t)GROUP * stride;

        // Compute + store group g.
        #pragma unroll
        for (int j = 0; j < GROUP; ++j) {
            LIF_STEP(buf[j]);
            f32x4 sv; sv.x = sx; sv.y = sy; sv.z = sz; sv.w = sw;
            f32x4 vv; vv.x = vx; vv.y = vy; vv.z = vz; vv.w = vw;
            __builtin_nontemporal_store(sv, &s_out[storeOff]);
            __builtin_nontemporal_store(vv, &v_out[storeOff]);
            __builtin_nontemporal_store(sv, &s_out2[storeOff]);
            storeOff += stride;
        }

        #pragma unroll
        for (int j = 0; j < GROUP; ++j)
            buf[j] = nbuf[j];   // SSA-renamed away after full unroll
    }
}

extern "C" void kernel_launch(void* const* d_in, const int* in_sizes, int n_in,
                              void* d_out, int out_size, void* d_ws, size_t ws_size,
                              hipStream_t stream) {
    const float* I = (const float*)d_in[0];
    float* out = (float*)d_out;

    const int TN = in_sizes[0];        // T * N
    const int N = TN / T_STEPS;
    const int n4 = N / 4;

    float* s0 = out;
    float* vm = out + (size_t)TN;
    float* s1 = out + 2 * (size_t)TN;

    const int block = 256;
    const int grid = (n4 + block - 1) / block;

    lif_kernel<<<grid, block, 0, stream>>>(
        (const f32x4*)I, (f32x4*)s0, (f32x4*)vm, (f32x4*)s1, n4);
}